// Round 4
// baseline (318.418 us; speedup 1.0000x reference)
//
#include <hip/hip_runtime.h>

#define NB   64
#define CIN  128
#define COUT 128
#define HH   64
#define WW   64
#define HW   4096

typedef float f4v __attribute__((ext_vector_type(4)));

// -------- workspace layout (float offsets) --------
// bs : [N][CIN][16]           @ 0       (131072)
// B  : [9][N][HW] basis flds  @ 147456  (2359296)  j=0..7 -> W_i2 rows, j=8 -> b_i2

// K1: single pass over x. Per block: (n, rowblock rb), ALL 128 channels.
// Produces bs[n, c, rb*4+cb] and 9 basis-field row slices.
__global__ __launch_bounds__(256) void k_stats(const float* __restrict__ x,
                                               const float* __restrict__ W_i2,
                                               const float* __restrict__ b_i2,
                                               float* __restrict__ bs,
                                               float* __restrict__ B) {
    const int bid = blockIdx.x;        // n*4 + rb
    const int n  = bid >> 2;
    const int rb = bid & 3;
    const int tid = threadIdx.x;
    const int r = tid >> 4;            // 0..15 (row within 16-row tile)
    const int colq = tid & 15;         // float4 column
    const int y0 = rb * 16;

    __shared__ float lw[9][128];
    __shared__ float bsw[4][4][128];   // [wave][colblock][c]

    if (tid < 128) {
        lw[8][tid] = b_i2[tid];
        #pragma unroll
        for (int j = 0; j < 8; ++j) lw[j][tid] = W_i2[j * CIN + tid];
    }
    __syncthreads();

    float4 acc[9];
    #pragma unroll
    for (int j = 0; j < 9; ++j) acc[j] = make_float4(0.f, 0.f, 0.f, 0.f);

    const size_t xbase = (size_t)n * CIN * HW + (size_t)(y0 + r) * WW + colq * 4;
    const int wv = tid >> 6;
    const int cb = colq >> 2;
    const bool rep = (tid & 0x33) == 0;   // one lane per (wave, colblock)

    for (int c = 0; c < 128; ++c) {
        f4v v = __builtin_nontemporal_load((const f4v*)(x + xbase + (size_t)c * HW));
        #pragma unroll
        for (int j = 0; j < 9; ++j) {
            const float w = lw[j][c];
            acc[j].x += w * v.x; acc[j].y += w * v.y;
            acc[j].z += w * v.z; acc[j].w += w * v.w;
        }
        float ls = (v.x + v.y) + (v.z + v.w);
        ls += __shfl_xor(ls, 1,  64);
        ls += __shfl_xor(ls, 2,  64);
        ls += __shfl_xor(ls, 16, 64);
        ls += __shfl_xor(ls, 32, 64);
        if (rep) bsw[wv][cb][c] = ls;     // rows wv*4..wv*4+3, cols cb*16..+15
    }
    __syncthreads();

    // 512 outputs: c 0..127 x cb 0..3; reduce the 4 row-wave partials
    #pragma unroll
    for (int k = 0; k < 2; ++k) {
        const int idx = tid + 256 * k;
        const int c = idx >> 2, cb2 = idx & 3;
        const float s = bsw[0][cb2][c] + bsw[1][cb2][c] + bsw[2][cb2][c] + bsw[3][cb2][c];
        bs[((size_t)n * CIN + c) * 16 + rb * 4 + cb2] = s;
    }

    const size_t bpix = (size_t)(y0 + r) * WW + colq * 4;
    #pragma unroll
    for (int j = 0; j < 9; ++j) {
        *(float4*)(B + ((size_t)j * NB + n) * HW + bpix) = acc[j];
    }
}

// K2 (fused): per-block coef prologue (co/hi/sp from bs), then t-tile from
// basis fields (+halo), 3x3 stencil, scale by co[o], nontemporal store.
__global__ __launch_bounds__(256) void k_out(
    const float* __restrict__ B, const float* __restrict__ bs,
    const float* __restrict__ W_sp, const float* __restrict__ b_sp,
    const float* __restrict__ W_o1, const float* __restrict__ b_o1,
    const float* __restrict__ W_o2, const float* __restrict__ b_o2,
    const float* __restrict__ W_i1, const float* __restrict__ b_i1,
    float* __restrict__ out)
{
    const int bid = blockIdx.x;          // n*8 + ytile
    const int n  = bid >> 3;
    const int y0 = (bid & 7) * 8;
    const int tid = threadIdx.x;

    __shared__ float lbs[128][17];
    __shared__ float lgap[128];
    __shared__ float lxsm[16];
    __shared__ float lh[16];             // [0..7] out-hidden, [8..15] in-hidden
    __shared__ float lco[128];
    __shared__ float lsp[9];
    __shared__ float ts[10][66];

    // ---- coef prologue ----
    if (tid < 128) {
        const int c = tid;
        const float* src = bs + ((size_t)n * CIN + c) * 16;
        float s = 0.0f;
        #pragma unroll
        for (int j = 0; j < 16; ++j) { const float v = src[j]; lbs[c][j] = v; s += v; }
        lgap[c] = s * (1.0f / 4096.0f);
    }
    __syncthreads();

    if (tid < 16) {
        float acc = 0.0f;
        for (int i = 0; i < 128; ++i) acc += lbs[i][tid];
        lxsm[tid] = acc * (1.0f / 32768.0f);
    }
    if (tid < 8) {
        float acc = b_o1[tid];
        for (int i = 0; i < 128; ++i) acc += lgap[i] * W_o1[i * 8 + tid];
        lh[tid] = fmaxf(acc, 0.0f);
    } else if (tid < 16) {
        const int j = tid - 8;
        float acc = b_i1[j];
        for (int i = 0; i < 128; ++i) acc += lgap[i] * W_i1[i * 8 + j];
        lh[tid] = fmaxf(acc, 0.0f);
    }
    __syncthreads();

    if (tid < 128) {
        float acco = b_o2[tid];
        #pragma unroll
        for (int j = 0; j < 8; ++j) acco += lh[j] * W_o2[j * 128 + tid];
        lco[tid] = acco;
    }
    if (tid < 9) {
        float acc = b_sp[tid];
        #pragma unroll
        for (int j = 0; j < 16; ++j) acc += lxsm[j] * W_sp[j * 9 + tid];
        lsp[tid] = acc;
    }
    __syncthreads();

    // ---- build rows y0-1 .. y0+8 of t (160 float4s) from 9 basis fields ----
    if (tid < 160) {
        const int ry = tid >> 4, cq = tid & 15;
        const int gy = y0 - 1 + ry;
        float4 tv = make_float4(0.f, 0.f, 0.f, 0.f);
        if (gy >= 0 && gy < HH) {
            const size_t pix = (size_t)gy * WW + cq * 4;
            const float* Bn = B + (size_t)n * HW + pix;
            float4 a = *(const float4*)(Bn + (size_t)8 * NB * HW);
            tv = a;
            #pragma unroll
            for (int j = 0; j < 8; ++j) {
                const float h = lh[8 + j];
                float4 u = *(const float4*)(Bn + (size_t)j * NB * HW);
                tv.x += h * u.x; tv.y += h * u.y;
                tv.z += h * u.z; tv.w += h * u.w;
            }
        }
        ts[ry][cq * 4 + 0] = tv.x; ts[ry][cq * 4 + 1] = tv.y;
        ts[ry][cq * 4 + 2] = tv.z; ts[ry][cq * 4 + 3] = tv.w;
    }
    __syncthreads();

    const int i = tid & 127;             // float4 index in 8x64 tile
    const int row = i >> 4;
    const int cc0 = (i & 15) * 4;
    float sv[4];
    #pragma unroll
    for (int u = 0; u < 4; ++u) {
        const int cc = cc0 + u;
        float acc = 0.0f;
        #pragma unroll
        for (int dy = 0; dy < 3; ++dy) {
            #pragma unroll
            for (int dx = 0; dx < 3; ++dx) {
                const int cx = cc + dx - 1;
                if (cx >= 0 && cx < WW)
                    acc += lsp[dy * 3 + dx] * ts[row + dy][cx];
            }
        }
        sv[u] = acc;
    }

    const int ohalf = (tid >> 7) * 64;
    float* outp = out + (size_t)n * COUT * HW + (size_t)y0 * WW + (size_t)i * 4;
    #pragma unroll 4
    for (int op = 0; op < 64; ++op) {
        const int o = ohalf + op;
        const float scl = lco[o];
        f4v v; v.x = sv[0] * scl; v.y = sv[1] * scl; v.z = sv[2] * scl; v.w = sv[3] * scl;
        __builtin_nontemporal_store(v, (f4v*)(outp + (size_t)o * HW));
    }
}

extern "C" void kernel_launch(void* const* d_in, const int* in_sizes, int n_in,
                              void* d_out, int out_size, void* d_ws, size_t ws_size,
                              hipStream_t stream) {
    const float* x    = (const float*)d_in[0];
    const float* W_sp = (const float*)d_in[1];
    const float* b_sp = (const float*)d_in[2];
    const float* W_o1 = (const float*)d_in[3];
    const float* b_o1 = (const float*)d_in[4];
    const float* W_o2 = (const float*)d_in[5];
    const float* b_o2 = (const float*)d_in[6];
    const float* W_i1 = (const float*)d_in[7];
    const float* b_i1 = (const float*)d_in[8];
    const float* W_i2 = (const float*)d_in[9];
    const float* b_i2 = (const float*)d_in[10];

    float* ws = (float*)d_ws;
    float* bs = ws;
    float* B  = ws + 147456;
    float* out = (float*)d_out;

    k_stats<<<NB * 4, 256, 0, stream>>>(x, W_i2, b_i2, bs, B);
    k_out<<<NB * 8, 256, 0, stream>>>(B, bs, W_sp, b_sp, W_o1, b_o1,
                                      W_o2, b_o2, W_i1, b_i1, out);
}

// Round 5
// 281.481 us; speedup vs baseline: 1.1312x; 1.1312x over previous
//
#include <hip/hip_runtime.h>

#define NB   64
#define CIN  128
#define COUT 128
#define HH   64
#define WW   64
#define HW   4096

typedef float f4v __attribute__((ext_vector_type(4)));

// -------- workspace layout (float offsets) --------
// gapp : [N][8][128]  @ 0      (65536)   per-(8-row-tile) per-channel sums
// xsmp : [N][8][4]    @ 65536  (2048)    per-(8-row-tile, 16-col-block) channel-summed
// B    : [9][N][HW]   @ 73728  (2359296) basis fields, j=0..7 -> W_i2 rows, j=8 -> b_i2

// K1: single pass over x. Block = (n, rt) 8-row tile; channel dim split across
// the two thread-halves (waves 0-1: c 0..63, waves 2-3: c 64..127).
__global__ __launch_bounds__(256) void k_stats(const float* __restrict__ x,
                                               const float* __restrict__ W_i2,
                                               const float* __restrict__ b_i2,
                                               float* __restrict__ gapp,
                                               float* __restrict__ xsmp,
                                               float* __restrict__ B) {
    const int bid = blockIdx.x;        // n*8 + rt
    const int n  = bid >> 3;
    const int rt = bid & 7;
    const int tid = threadIdx.x;
    const int cs = tid >> 7;           // channel half
    const int p  = tid & 127;          // float4-pixel index in 8x64 tile
    const int row = p >> 4;            // 0..7
    const int colq = p & 15;           // float4 column
    const int wv = tid >> 6;           // wave 0..3
    const int cb = colq >> 2;          // 16-col block

    __shared__ float lw[2][9][64];
    __shared__ float bsw[4][4][72];    // [wave][colb][c], stride 72 (=8 mod 32)
    __shared__ float cacc[9][4][128];  // half-1 accumulators for combine

    for (int k = tid; k < 1152; k += 256) {
        const int half = k / 576, jj = (k % 576) >> 6, c = k & 63;
        lw[half][jj][c] = (jj == 8) ? b_i2[half * 64 + c]
                                    : W_i2[jj * CIN + half * 64 + c];
    }
    __syncthreads();

    float4 acc[9];
    #pragma unroll
    for (int j = 0; j < 9; ++j) acc[j] = make_float4(0.f, 0.f, 0.f, 0.f);

    const size_t xbase = ((size_t)n * CIN + cs * 64) * HW
                       + (size_t)(rt * 8 + row) * WW + colq * 4;
    const bool rep = (tid & 0x33) == 0;   // one lane per (wave, colb)

    #pragma unroll 4
    for (int c = 0; c < 64; ++c) {
        f4v v = __builtin_nontemporal_load((const f4v*)(x + xbase + (size_t)c * HW));
        #pragma unroll
        for (int j = 0; j < 9; ++j) {
            const float w = lw[cs][j][c];
            acc[j].x += w * v.x; acc[j].y += w * v.y;
            acc[j].z += w * v.z; acc[j].w += w * v.w;
        }
        float ls = (v.x + v.y) + (v.z + v.w);
        ls += __shfl_xor(ls, 1,  64);      // colq&1
        ls += __shfl_xor(ls, 2,  64);      // colq&2
        ls += __shfl_xor(ls, 16, 64);      // row bit 0
        ls += __shfl_xor(ls, 32, 64);      // row bit 1
        if (rep) bsw[wv][cb][c] = ls;      // per-(wave,colb) channel partial
    }
    __syncthreads();

    // half-1 parks its accumulators in LDS for the combine
    if (cs == 1) {
        #pragma unroll
        for (int j = 0; j < 9; ++j) {
            cacc[j][0][p] = acc[j].x; cacc[j][1][p] = acc[j].y;
            cacc[j][2][p] = acc[j].z; cacc[j][3][p] = acc[j].w;
        }
    }

    // gap partials: per-channel sum over this 8x64 tile
    if (tid < 128) {
        const int half = tid >> 6, c = tid & 63;
        float s = 0.0f;
        #pragma unroll
        for (int q = 0; q < 4; ++q)
            s += bsw[half * 2][q][c] + bsw[half * 2 + 1][q][c];
        gapp[((size_t)n * 8 + rt) * 128 + half * 64 + c] = s;
    }
    // xsm partials: wave w reduces col-block w over all channels/waves
    {
        const int colb = wv, c = tid & 63;
        float s2 = bsw[0][colb][c] + bsw[1][colb][c]
                 + bsw[2][colb][c] + bsw[3][colb][c];
        s2 += __shfl_xor(s2, 1,  64);
        s2 += __shfl_xor(s2, 2,  64);
        s2 += __shfl_xor(s2, 4,  64);
        s2 += __shfl_xor(s2, 8,  64);
        s2 += __shfl_xor(s2, 16, 64);
        s2 += __shfl_xor(s2, 32, 64);
        if (c == 0) xsmp[((size_t)n * 8 + rt) * 4 + colb] = s2;
    }
    __syncthreads();

    // half-0 combines and stores the 9 basis-field slices (coalesced)
    if (cs == 0) {
        const size_t bpix = (size_t)(rt * 8 + row) * WW + colq * 4;
        #pragma unroll
        for (int j = 0; j < 9; ++j) {
            f4v v;
            v.x = acc[j].x + cacc[j][0][p];
            v.y = acc[j].y + cacc[j][1][p];
            v.z = acc[j].z + cacc[j][2][p];
            v.w = acc[j].w + cacc[j][3][p];
            __builtin_nontemporal_store(v, (f4v*)(B + ((size_t)j * NB + n) * HW + bpix));
        }
    }
}

// K2 (fused): coef prologue (co/hi/sp from gapp/xsmp), t-tile from 9 basis
// fields (+halo), 3x3 stencil, scale by co[o], nontemporal store.
__global__ __launch_bounds__(256) void k_out(
    const float* __restrict__ B,
    const float* __restrict__ gapp, const float* __restrict__ xsmp,
    const float* __restrict__ W_sp, const float* __restrict__ b_sp,
    const float* __restrict__ W_o1, const float* __restrict__ b_o1,
    const float* __restrict__ W_o2, const float* __restrict__ b_o2,
    const float* __restrict__ W_i1, const float* __restrict__ b_i1,
    float* __restrict__ out)
{
    const int bid = blockIdx.x;          // n*8 + ytile
    const int n  = bid >> 3;
    const int y0 = (bid & 7) * 8;
    const int tid = threadIdx.x;

    __shared__ float lgap[128];
    __shared__ float lxsm[16];
    __shared__ float lh[16];             // [0..7] out-hidden, [8..15] in-hidden
    __shared__ float lco[128];
    __shared__ float lsp[9];
    __shared__ float ts[10][66];

    if (tid < 128) {
        float s = 0.0f;
        #pragma unroll
        for (int rt = 0; rt < 8; ++rt)
            s += gapp[((size_t)n * 8 + rt) * 128 + tid];
        lgap[tid] = s * (1.0f / 4096.0f);
    }
    if (tid < 16) {
        const int rowblk = tid >> 2, colb = tid & 3;
        const float s = xsmp[((size_t)n * 8 + rowblk * 2) * 4 + colb]
                      + xsmp[((size_t)n * 8 + rowblk * 2 + 1) * 4 + colb];
        lxsm[tid] = s * (1.0f / 32768.0f);
    }
    __syncthreads();

    if (tid < 8) {
        float acc = b_o1[tid];
        for (int i = 0; i < 128; ++i) acc += lgap[i] * W_o1[i * 8 + tid];
        lh[tid] = fmaxf(acc, 0.0f);
    } else if (tid < 16) {
        const int j = tid - 8;
        float acc = b_i1[j];
        for (int i = 0; i < 128; ++i) acc += lgap[i] * W_i1[i * 8 + j];
        lh[tid] = fmaxf(acc, 0.0f);
    }
    __syncthreads();

    if (tid < 128) {
        float acco = b_o2[tid];
        #pragma unroll
        for (int j = 0; j < 8; ++j) acco += lh[j] * W_o2[j * 128 + tid];
        lco[tid] = acco;
    }
    if (tid < 9) {
        float acc = b_sp[tid];
        #pragma unroll
        for (int j = 0; j < 16; ++j) acc += lxsm[j] * W_sp[j * 9 + tid];
        lsp[tid] = acc;
    }
    __syncthreads();

    // ---- build rows y0-1 .. y0+8 of t (160 float4s) from 9 basis fields ----
    if (tid < 160) {
        const int ry = tid >> 4, cq = tid & 15;
        const int gy = y0 - 1 + ry;
        float4 tv = make_float4(0.f, 0.f, 0.f, 0.f);
        if (gy >= 0 && gy < HH) {
            const size_t pix = (size_t)gy * WW + cq * 4;
            const float* Bn = B + (size_t)n * HW + pix;
            float4 a = *(const float4*)(Bn + (size_t)8 * NB * HW);
            tv = a;
            #pragma unroll
            for (int j = 0; j < 8; ++j) {
                const float h = lh[8 + j];
                float4 u = *(const float4*)(Bn + (size_t)j * NB * HW);
                tv.x += h * u.x; tv.y += h * u.y;
                tv.z += h * u.z; tv.w += h * u.w;
            }
        }
        ts[ry][cq * 4 + 0] = tv.x; ts[ry][cq * 4 + 1] = tv.y;
        ts[ry][cq * 4 + 2] = tv.z; ts[ry][cq * 4 + 3] = tv.w;
    }
    __syncthreads();

    const int i = tid & 127;             // float4 index in 8x64 tile
    const int row = i >> 4;
    const int cc0 = (i & 15) * 4;
    float sv[4];
    #pragma unroll
    for (int u = 0; u < 4; ++u) {
        const int cc = cc0 + u;
        float acc = 0.0f;
        #pragma unroll
        for (int dy = 0; dy < 3; ++dy) {
            #pragma unroll
            for (int dx = 0; dx < 3; ++dx) {
                const int cx = cc + dx - 1;
                if (cx >= 0 && cx < WW)
                    acc += lsp[dy * 3 + dx] * ts[row + dy][cx];
            }
        }
        sv[u] = acc;
    }

    const int ohalf = (tid >> 7) * 64;
    float* outp = out + (size_t)n * COUT * HW + (size_t)y0 * WW + (size_t)i * 4;
    #pragma unroll 4
    for (int op = 0; op < 64; ++op) {
        const int o = ohalf + op;
        const float scl = lco[o];
        f4v v; v.x = sv[0] * scl; v.y = sv[1] * scl; v.z = sv[2] * scl; v.w = sv[3] * scl;
        __builtin_nontemporal_store(v, (f4v*)(outp + (size_t)o * HW));
    }
}

extern "C" void kernel_launch(void* const* d_in, const int* in_sizes, int n_in,
                              void* d_out, int out_size, void* d_ws, size_t ws_size,
                              hipStream_t stream) {
    const float* x    = (const float*)d_in[0];
    const float* W_sp = (const float*)d_in[1];
    const float* b_sp = (const float*)d_in[2];
    const float* W_o1 = (const float*)d_in[3];
    const float* b_o1 = (const float*)d_in[4];
    const float* W_o2 = (const float*)d_in[5];
    const float* b_o2 = (const float*)d_in[6];
    const float* W_i1 = (const float*)d_in[7];
    const float* b_i1 = (const float*)d_in[8];
    const float* W_i2 = (const float*)d_in[9];
    const float* b_i2 = (const float*)d_in[10];

    float* ws = (float*)d_ws;
    float* gapp = ws;
    float* xsmp = ws + 65536;
    float* B    = ws + 73728;
    float* out  = (float*)d_out;

    k_stats<<<NB * 8, 256, 0, stream>>>(x, W_i2, b_i2, gapp, xsmp, B);
    k_out<<<NB * 8, 256, 0, stream>>>(B, gapp, xsmp, W_sp, b_sp, W_o1, b_o1,
                                      W_o2, b_o2, W_i1, b_i1, out);
}